// Round 2
// baseline (477.635 us; speedup 1.0000x reference)
//
#include <hip/hip_runtime.h>

#define NROWS 8192
#define DIM   128
#define RS    132    // spmm LDS reduce row stride (dwords)
#define PSTR  520    // k_prep LDS row stride (shorts) = 260 dwords -> 2-way banks

typedef __attribute__((ext_vector_type(8))) short  short8;
typedef __attribute__((ext_vector_type(4))) float  floatx4;

// pack two fp32 -> two bf16 (RNE), low word = a
__device__ __forceinline__ unsigned pk_bf16(float a, float b) {
  unsigned ua = __float_as_uint(a);
  ua += 0x7fffu + ((ua >> 16) & 1u);
  unsigned ub = __float_as_uint(b);
  ub += 0x7fffu + ((ub >> 16) & 1u);
  return (ua >> 16) | (ub & 0xffff0000u);
}

// ---- kernel 1: fused rowsum + bf16-tile conversion of A --------------------
// Tile layout: Abf[((iblk*256 + jblk)*64 + L)*8 + e], L = quad*16 + l15:
//   row i = iblk*16 + l15, col j = jblk*32 + quad*8 + e  (MFMA B-operand frag)
__global__ __launch_bounds__(256) void k_prep(const float* __restrict__ A,
                                              float* __restrict__ d,
                                              unsigned short* __restrict__ Abf) {
  __shared__ unsigned short B[16 * PSTR];   // 16.6 KB
  __shared__ float rsum[16 * 17];
  int iblk = blockIdx.x;            // 0..511
  int wb   = blockIdx.y;            // 0..15
  int i0   = iblk * 16;
  int jwin = wb * 512;
  int t = threadIdx.x;
  int r = t >> 4, l16 = t & 15;

  const float* ap = A + (size_t)(i0 + r) * NROWS + jwin + l16 * 8;
  float sum = 0.f;
#pragma unroll
  for (int it = 0; it < 4; ++it) {
    float4 lo = *(const float4*)(ap + it * 128);
    float4 hi = *(const float4*)(ap + it * 128 + 4);
    sum += (lo.x + lo.y) + (lo.z + lo.w) + (hi.x + hi.y) + (hi.z + hi.w);
    uint4 p = make_uint4(pk_bf16(lo.x, lo.y), pk_bf16(lo.z, lo.w),
                         pk_bf16(hi.x, hi.y), pk_bf16(hi.z, hi.w));
    *(uint4*)&B[r * PSTR + l16 * 8 + it * 128] = p;
  }
  rsum[r * 17 + l16] = sum;
  __syncthreads();
  if (t < 16) {
    float s2 = 0.f;
#pragma unroll
    for (int c = 0; c < 16; ++c) s2 += rsum[t * 17 + c];
    atomicAdd(&d[i0 + t], s2);
  }
  // tiled write: 16 tiles (jb), 16 threads each, 4 lane-slots per thread
  int jb = t >> 4, p = t & 15;
  unsigned short* tbase = Abf + ((size_t)iblk * 256 + wb * 16 + jb) * 512;
#pragma unroll
  for (int q = 0; q < 4; ++q) {
    uint4 v = *(const uint4*)&B[p * PSTR + jb * 32 + q * 8];
    *(uint4*)(tbase + (size_t)(q * 16 + p) * 8) = v;
  }
}

__global__ __launch_bounds__(256) void k_sconv(const float* __restrict__ d,
                                               float* __restrict__ s) {
  int i = blockIdx.x * 256 + threadIdx.x;
  s[i] = 1.0f / (sqrtf(d[i]) + 1e-8f);
}

// ---- kernel 2: gT tiles: gTt tile[kblk][jblk], lane L: kout=kblk*16+(L&15),
//      j = jblk*32 + (L>>4)*8 + e   (MFMA A-operand frag), value s_j*fc[j][k]
__global__ __launch_bounds__(256) void k_fc(const float* __restrict__ V,
                                            const float* __restrict__ W,
                                            const float* __restrict__ b,
                                            const float* __restrict__ s,
                                            unsigned short* __restrict__ gTt) {
  __shared__ float Wl[DIM * DIM];          // 64 KB
  __shared__ float Vl[32 * DIM];           // 16 KB
  __shared__ unsigned short Fl[32 * DIM];  // 8 KB  [j_local][k]
  int r0 = blockIdx.x * 32;
  {
    const float4* Wg = (const float4*)W;
    float4* Wd = (float4*)Wl;
#pragma unroll
    for (int i = 0; i < DIM * DIM / 4 / 256; ++i)
      Wd[threadIdx.x + i * 256] = Wg[threadIdx.x + i * 256];
    const float4* Vg = (const float4*)(V + (size_t)r0 * DIM);
    float4* Vd = (float4*)Vl;
#pragma unroll
    for (int i = 0; i < 32 * DIM / 4 / 256; ++i)
      Vd[threadIdx.x + i * 256] = Vg[threadIdx.x + i * 256];
  }
  __syncthreads();

  int cg = threadIdx.x & 31;
  int rg = threadIdx.x >> 5;
  float acc[4][4] = {};
  for (int dd = 0; dd < DIM; ++dd) {
    float4 w = *(const float4*)&Wl[dd * DIM + cg * 4];
#pragma unroll
    for (int rr = 0; rr < 4; ++rr) {
      float v = Vl[(rg * 4 + rr) * DIM + dd];
      acc[rr][0] += v * w.x; acc[rr][1] += v * w.y;
      acc[rr][2] += v * w.z; acc[rr][3] += v * w.w;
    }
  }
  float bb[4], sv[4];
#pragma unroll
  for (int cc = 0; cc < 4; ++cc) bb[cc] = b[cg * 4 + cc];
#pragma unroll
  for (int rr = 0; rr < 4; ++rr) sv[rr] = s[r0 + rg * 4 + rr];
#pragma unroll
  for (int rr = 0; rr < 4; ++rr)
#pragma unroll
    for (int cc = 0; cc < 4; cc += 2) {
      unsigned p = pk_bf16((acc[rr][cc]     + bb[cc])     * sv[rr],
                           (acc[rr][cc + 1] + bb[cc + 1]) * sv[rr]);
      *(unsigned*)&Fl[(rg * 4 + rr) * DIM + cg * 4 + cc] = p;
    }
  __syncthreads();

  int kblk = threadIdx.x >> 5, s5 = threadIdx.x & 31;
  int jblk = r0 >> 5;
#pragma unroll
  for (int h = 0; h < 2; ++h) {
    int L = s5 + h * 32;
    int l15 = L & 15, quad = L >> 4;
    int k = kblk * 16 + l15;
    unsigned w0 = (unsigned)Fl[(quad * 8 + 0) * DIM + k] | ((unsigned)Fl[(quad * 8 + 1) * DIM + k] << 16);
    unsigned w1 = (unsigned)Fl[(quad * 8 + 2) * DIM + k] | ((unsigned)Fl[(quad * 8 + 3) * DIM + k] << 16);
    unsigned w2 = (unsigned)Fl[(quad * 8 + 4) * DIM + k] | ((unsigned)Fl[(quad * 8 + 5) * DIM + k] << 16);
    unsigned w3 = (unsigned)Fl[(quad * 8 + 6) * DIM + k] | ((unsigned)Fl[(quad * 8 + 7) * DIM + k] << 16);
    *(uint4*)(gTt + ((size_t)(kblk * 256 + jblk) * 64 + L) * 8) = make_uint4(w0, w1, w2, w3);
  }
}

// ---- kernel 3 (fused): out[bi tile] = s_i * (gTt x Abf) over FULL j range --
// block bi: tile 32 i x 128 kout; wave w covers jblk in [w*64, w*64+64)
// 4-wave partials cross-reduced in LDS, scaled by s_i, written to out.
__global__ __launch_bounds__(256, 4) void k_spmm(const unsigned short* __restrict__ Abf,
                                                 const unsigned short* __restrict__ gTt,
                                                 const float* __restrict__ s,
                                                 float* __restrict__ out) {
  __shared__ float red[4 * 32 * RS];   // 67.6 KB
  int t = threadIdx.x, w = t >> 6, lane = t & 63;
  int bi = blockIdx.x;                 // 0..255
  int jblk0 = w * 64;

  const unsigned short* ab = Abf + ((size_t)bi * 2 * 256 + jblk0) * 512 + lane * 8;
  const unsigned short* gb = gTt + (size_t)jblk0 * 512 + lane * 8;

  floatx4 acc[8][2];
#pragma unroll
  for (int kb = 0; kb < 8; ++kb)
#pragma unroll
    for (int ib = 0; ib < 2; ++ib)
      acc[kb][ib] = (floatx4){0.f, 0.f, 0.f, 0.f};

#pragma unroll 2
  for (int it = 0; it < 64; ++it) {
    short8 af0 = *(const short8*)(ab);
    short8 af1 = *(const short8*)(ab + (size_t)256 * 512);
    short8 gf[8];
#pragma unroll
    for (int kb = 0; kb < 8; ++kb)
      gf[kb] = *(const short8*)(gb + (size_t)kb * 256 * 512);
#pragma unroll
    for (int kb = 0; kb < 8; ++kb) {
      acc[kb][0] = __builtin_amdgcn_mfma_f32_16x16x32_bf16(gf[kb], af0, acc[kb][0], 0, 0, 0);
      acc[kb][1] = __builtin_amdgcn_mfma_f32_16x16x32_bf16(gf[kb], af1, acc[kb][1], 0, 0, 0);
    }
    ab += 512; gb += 512;
  }

  int l15 = lane & 15, quad = lane >> 4;
  float* myred = red + w * 32 * RS;
#pragma unroll
  for (int ib = 0; ib < 2; ++ib)
#pragma unroll
    for (int kb = 0; kb < 8; ++kb) {
      float4 v = make_float4(acc[kb][ib][0], acc[kb][ib][1], acc[kb][ib][2], acc[kb][ib][3]);
      *(float4*)(myred + (ib * 16 + l15) * RS + kb * 16 + quad * 4) = v;
    }
  __syncthreads();

  int ii = t >> 3, kg = (t & 7) * 16;
  float4 sum[4];
#pragma unroll
  for (int c = 0; c < 4; ++c) sum[c] = make_float4(0.f, 0.f, 0.f, 0.f);
#pragma unroll
  for (int ww = 0; ww < 4; ++ww)
#pragma unroll
    for (int c = 0; c < 4; ++c) {
      float4 v = *(const float4*)(red + ww * 32 * RS + ii * RS + kg + c * 4);
      sum[c].x += v.x; sum[c].y += v.y; sum[c].z += v.z; sum[c].w += v.w;
    }
  float si = s[bi * 32 + ii];
  float* pout = out + ((size_t)(bi * 32 + ii)) * 128 + kg;
#pragma unroll
  for (int c = 0; c < 4; ++c) {
    float4 r = make_float4(si * sum[c].x, si * sum[c].y, si * sum[c].z, si * sum[c].w);
    *(float4*)(pout + c * 4) = r;
  }
}

extern "C" void kernel_launch(void* const* d_in, const int* in_sizes, int n_in,
                              void* d_out, int out_size, void* d_ws, size_t ws_size,
                              hipStream_t stream) {
  const float* values    = (const float*)d_in[0];
  const float* adjacency = (const float*)d_in[1];
  const float* W         = (const float*)d_in[2];
  const float* b         = (const float*)d_in[3];
  float* out = (float*)d_out;

  char* ws = (char*)d_ws;
  float* d            = (float*)ws;                         // 32 KB
  float* s            = (float*)(ws + 32768);               // 32 KB
  unsigned short* gTt = (unsigned short*)(ws + 65536);      // 2 MB
  unsigned short* Abf = (unsigned short*)(ws + 65536 + 2097152);  // 128 MB

  hipMemsetAsync(d, 0, NROWS * sizeof(float), stream);
  k_prep<<<dim3(512, 16), 256, 0, stream>>>(adjacency, d, Abf);
  k_sconv<<<NROWS / 256, 256, 0, stream>>>(d, s);
  k_fc<<<NROWS / 32, 256, 0, stream>>>(values, W, b, s, gTt);
  k_spmm<<<256, 256, 0, stream>>>(Abf, gTt, s, out);
}

// Round 3
// 431.603 us; speedup vs baseline: 1.1067x; 1.1067x over previous
//
#include <hip/hip_runtime.h>

#define NROWS 8192
#define DIM   128
#define RS    132    // spmm LDS reduce row stride (dwords)

typedef __attribute__((ext_vector_type(8))) short  short8;
typedef __attribute__((ext_vector_type(4))) float  floatx4;

// pack two fp32 -> two bf16 (RNE), low word = a
__device__ __forceinline__ unsigned pk_bf16(float a, float b) {
  unsigned ua = __float_as_uint(a);
  ua += 0x7fffu + ((ua >> 16) & 1u);
  unsigned ub = __float_as_uint(b);
  ub += 0x7fffu + ((ub >> 16) & 1u);
  return (ua >> 16) | (ub & 0xffff0000u);
}

// ---- kernel 1: pure rowsum of A (streaming read, no writes besides d) -----
// one wave per row; 2048 blocks x 4 waves
__global__ __launch_bounds__(256) void k_rowsum(const float* __restrict__ A,
                                                float* __restrict__ d) {
  int w = threadIdx.x >> 6, lane = threadIdx.x & 63;
  int row = blockIdx.x * 4 + w;
  const float* ap = A + (size_t)row * NROWS + lane * 4;
  float sum = 0.f;
#pragma unroll
  for (int it = 0; it < 32; ++it) {
    float4 v = *(const float4*)(ap + (size_t)it * 256);
    sum += (v.x + v.y) + (v.z + v.w);
  }
#pragma unroll
  for (int off = 32; off; off >>= 1) sum += __shfl_down(sum, off, 64);
  if (lane == 0) d[row] = sum;
}

__global__ __launch_bounds__(256) void k_sconv(const float* __restrict__ d,
                                               float* __restrict__ s) {
  int i = blockIdx.x * 256 + threadIdx.x;
  s[i] = 1.0f / (sqrtf(d[i]) + 1e-8f);
}

// ---- kernel 2: gT tiles: gTt tile[kblk][jblk], lane L: kout=kblk*16+(L&15),
//      j = jblk*32 + (L>>4)*8 + e   (MFMA A-operand frag), value s_j*fc[j][k]
__global__ __launch_bounds__(256) void k_fc(const float* __restrict__ V,
                                            const float* __restrict__ W,
                                            const float* __restrict__ b,
                                            const float* __restrict__ s,
                                            unsigned short* __restrict__ gTt) {
  __shared__ float Wl[DIM * DIM];          // 64 KB
  __shared__ float Vl[32 * DIM];           // 16 KB
  __shared__ unsigned short Fl[32 * DIM];  // 8 KB  [j_local][k]
  int r0 = blockIdx.x * 32;
  {
    const float4* Wg = (const float4*)W;
    float4* Wd = (float4*)Wl;
#pragma unroll
    for (int i = 0; i < DIM * DIM / 4 / 256; ++i)
      Wd[threadIdx.x + i * 256] = Wg[threadIdx.x + i * 256];
    const float4* Vg = (const float4*)(V + (size_t)r0 * DIM);
    float4* Vd = (float4*)Vl;
#pragma unroll
    for (int i = 0; i < 32 * DIM / 4 / 256; ++i)
      Vd[threadIdx.x + i * 256] = Vg[threadIdx.x + i * 256];
  }
  __syncthreads();

  int cg = threadIdx.x & 31;
  int rg = threadIdx.x >> 5;
  float acc[4][4] = {};
  for (int dd = 0; dd < DIM; ++dd) {
    float4 w = *(const float4*)&Wl[dd * DIM + cg * 4];
#pragma unroll
    for (int rr = 0; rr < 4; ++rr) {
      float v = Vl[(rg * 4 + rr) * DIM + dd];
      acc[rr][0] += v * w.x; acc[rr][1] += v * w.y;
      acc[rr][2] += v * w.z; acc[rr][3] += v * w.w;
    }
  }
  float bb[4], sv[4];
#pragma unroll
  for (int cc = 0; cc < 4; ++cc) bb[cc] = b[cg * 4 + cc];
#pragma unroll
  for (int rr = 0; rr < 4; ++rr) sv[rr] = s[r0 + rg * 4 + rr];
#pragma unroll
  for (int rr = 0; rr < 4; ++rr)
#pragma unroll
    for (int cc = 0; cc < 4; cc += 2) {
      unsigned p = pk_bf16((acc[rr][cc]     + bb[cc])     * sv[rr],
                           (acc[rr][cc + 1] + bb[cc + 1]) * sv[rr]);
      *(unsigned*)&Fl[(rg * 4 + rr) * DIM + cg * 4 + cc] = p;
    }
  __syncthreads();

  int kblk = threadIdx.x >> 5, s5 = threadIdx.x & 31;
  int jblk = r0 >> 5;
#pragma unroll
  for (int h = 0; h < 2; ++h) {
    int L = s5 + h * 32;
    int l15 = L & 15, quad = L >> 4;
    int k = kblk * 16 + l15;
    unsigned w0 = (unsigned)Fl[(quad * 8 + 0) * DIM + k] | ((unsigned)Fl[(quad * 8 + 1) * DIM + k] << 16);
    unsigned w1 = (unsigned)Fl[(quad * 8 + 2) * DIM + k] | ((unsigned)Fl[(quad * 8 + 3) * DIM + k] << 16);
    unsigned w2 = (unsigned)Fl[(quad * 8 + 4) * DIM + k] | ((unsigned)Fl[(quad * 8 + 5) * DIM + k] << 16);
    unsigned w3 = (unsigned)Fl[(quad * 8 + 6) * DIM + k] | ((unsigned)Fl[(quad * 8 + 7) * DIM + k] << 16);
    *(uint4*)(gTt + ((size_t)(kblk * 256 + jblk) * 64 + L) * 8) = make_uint4(w0, w1, w2, w3);
  }
}

// ---- kernel 3 (fused): out[bi tile] = s_i * (gTt x A) over FULL j range ----
// A read directly as f32, converted to bf16 MFMA B-frags in-register.
// block bi: tile 32 i x 128 kout; wave w covers j in [w*2048, (w+1)*2048)
// lane L = quad*16+l15: af0 row = bi*32+l15, af1 row = bi*32+16+l15,
//   j = jwin + quad*8 + e (8 consecutive floats = 32B contiguous per lane)
__global__ __launch_bounds__(256, 2) void k_spmm(const float* __restrict__ A,
                                                 const unsigned short* __restrict__ gTt,
                                                 const float* __restrict__ s,
                                                 float* __restrict__ out) {
  __shared__ float red[4 * 32 * RS];   // 67.6 KB
  int t = threadIdx.x, w = t >> 6, lane = t & 63;
  int l15 = lane & 15, quad = lane >> 4;
  int bi = blockIdx.x;                 // 0..255
  int jblk0 = w * 64;                  // wave's first 32-col block

  const float* ap0 = A + (size_t)(bi * 32 + l15) * NROWS + jblk0 * 32 + quad * 8;
  const float* ap1 = ap0 + (size_t)16 * NROWS;
  const unsigned short* gb = gTt + (size_t)jblk0 * 512 + lane * 8;

  floatx4 acc[8][2];
#pragma unroll
  for (int kb = 0; kb < 8; ++kb)
#pragma unroll
    for (int ib = 0; ib < 2; ++ib)
      acc[kb][ib] = (floatx4){0.f, 0.f, 0.f, 0.f};

#pragma unroll 2
  for (int it = 0; it < 64; ++it) {
    float4 a0lo = *(const float4*)(ap0);
    float4 a0hi = *(const float4*)(ap0 + 4);
    float4 a1lo = *(const float4*)(ap1);
    float4 a1hi = *(const float4*)(ap1 + 4);
    short8 gf[8];
#pragma unroll
    for (int kb = 0; kb < 8; ++kb)
      gf[kb] = *(const short8*)(gb + (size_t)kb * 256 * 512);
    union { unsigned u[4]; short8 s8; } c0, c1;
    c0.u[0] = pk_bf16(a0lo.x, a0lo.y); c0.u[1] = pk_bf16(a0lo.z, a0lo.w);
    c0.u[2] = pk_bf16(a0hi.x, a0hi.y); c0.u[3] = pk_bf16(a0hi.z, a0hi.w);
    c1.u[0] = pk_bf16(a1lo.x, a1lo.y); c1.u[1] = pk_bf16(a1lo.z, a1lo.w);
    c1.u[2] = pk_bf16(a1hi.x, a1hi.y); c1.u[3] = pk_bf16(a1hi.z, a1hi.w);
#pragma unroll
    for (int kb = 0; kb < 8; ++kb) {
      acc[kb][0] = __builtin_amdgcn_mfma_f32_16x16x32_bf16(gf[kb], c0.s8, acc[kb][0], 0, 0, 0);
      acc[kb][1] = __builtin_amdgcn_mfma_f32_16x16x32_bf16(gf[kb], c1.s8, acc[kb][1], 0, 0, 0);
    }
    ap0 += 32; ap1 += 32; gb += 512;
  }

  float* myred = red + w * 32 * RS;
#pragma unroll
  for (int ib = 0; ib < 2; ++ib)
#pragma unroll
    for (int kb = 0; kb < 8; ++kb) {
      float4 v = make_float4(acc[kb][ib][0], acc[kb][ib][1], acc[kb][ib][2], acc[kb][ib][3]);
      *(float4*)(myred + (ib * 16 + l15) * RS + kb * 16 + quad * 4) = v;
    }
  __syncthreads();

  int ii = t >> 3, kg = (t & 7) * 16;
  float4 sum[4];
#pragma unroll
  for (int c = 0; c < 4; ++c) sum[c] = make_float4(0.f, 0.f, 0.f, 0.f);
#pragma unroll
  for (int ww = 0; ww < 4; ++ww)
#pragma unroll
    for (int c = 0; c < 4; ++c) {
      float4 v = *(const float4*)(red + ww * 32 * RS + ii * RS + kg + c * 4);
      sum[c].x += v.x; sum[c].y += v.y; sum[c].z += v.z; sum[c].w += v.w;
    }
  float si = s[bi * 32 + ii];
  float* pout = out + ((size_t)(bi * 32 + ii)) * 128 + kg;
#pragma unroll
  for (int c = 0; c < 4; ++c) {
    float4 r = make_float4(si * sum[c].x, si * sum[c].y, si * sum[c].z, si * sum[c].w);
    *(float4*)(pout + c * 4) = r;
  }
}

extern "C" void kernel_launch(void* const* d_in, const int* in_sizes, int n_in,
                              void* d_out, int out_size, void* d_ws, size_t ws_size,
                              hipStream_t stream) {
  const float* values    = (const float*)d_in[0];
  const float* adjacency = (const float*)d_in[1];
  const float* W         = (const float*)d_in[2];
  const float* b         = (const float*)d_in[3];
  float* out = (float*)d_out;

  char* ws = (char*)d_ws;
  float* d            = (float*)ws;                         // 32 KB
  float* s            = (float*)(ws + 32768);               // 32 KB
  unsigned short* gTt = (unsigned short*)(ws + 65536);      // 2 MB

  k_rowsum<<<NROWS / 4, 256, 0, stream>>>(adjacency, d);
  k_sconv<<<NROWS / 256, 256, 0, stream>>>(d, s);
  k_fc<<<NROWS / 32, 256, 0, stream>>>(values, W, b, s, gTt);
  k_spmm<<<256, 256, 0, stream>>>(adjacency, gTt, s, out);
}